// Round 2
// baseline (1007.665 us; speedup 1.0000x reference)
//
#include <hip/hip_runtime.h>

#define DIM 256
#define VDIM 300

// ws layout (float offsets)
#define OFF_BASE 0        // 256*256 floats
#define OFF_CAND 65536    // 4*256
#define OFF_DS   66560    // 1
#define OFF_BAR  66576    // 16 uint barrier counters
#define OFF_S    66592    // 16 float per-graph score accumulators
#define OFF_R    66624    // 16*256*256 r-vectors

__global__ __launch_bounds__(256) void base_kernel(const int* __restrict__ data,
    const float* __restrict__ data_vecs, const float* __restrict__ data_w,
    const float* __restrict__ data_b, float* __restrict__ ws) {
  __shared__ float s_v[VDIM];
  const int i = blockIdx.x, t = threadIdx.x;
  const int row = data[i];
  for (int k = t; k < VDIM; k += 256) s_v[k] = data_vecs[(size_t)row * VDIM + k];
  __syncthreads();
  float acc = data_b[t];
  for (int k = 0; k < VDIM; ++k) acc = fmaf(s_v[k], data_w[k * DIM + t], acc);
  ws[OFF_BASE + i * DIM + t] = acc;
}

__global__ __launch_bounds__(256) void prep_kernel(const float* __restrict__ edge_w,
    const float* __restrict__ edge_b, const float* __restrict__ sdw,
    const float* __restrict__ sdb, float* __restrict__ ws) {
  __shared__ float s_b[DIM];
  __shared__ float s_red[DIM];
  const int e = blockIdx.x, t = threadIdx.x;
  s_b[t] = ws[OFF_BASE + 255 * DIM + t];
  __syncthreads();
  if (e < 4) {
    // cand_e[t] = sum_d base255[d] * W_e[d][t] + b_e[t]
    float acc = edge_b[e * DIM + t];
    for (int d = 0; d < DIM; ++d)
      acc = fmaf(s_b[d], edge_w[e * DIM * DIM + d * DIM + t], acc);
    ws[OFF_CAND + e * DIM + t] = acc;
  } else {
    // data_score = dot(base255 + sdb, sdw)
    s_red[t] = (s_b[t] + sdb[t]) * sdw[t];
    __syncthreads();
    for (int off = 128; off > 0; off >>= 1) {
      if (t < off) s_red[t] += s_red[t + off];
      __syncthreads();
    }
    if (t == 0) ws[OFF_DS] = s_red[0];
  }
}

// per-graph barrier among 16 blocks: monotonic counter, agent scope
__device__ __forceinline__ void gbar(unsigned int* cnt, unsigned int target) {
  __threadfence();
  __syncthreads();
  if (threadIdx.x == 0) {
    __hip_atomic_fetch_add(cnt, 1u, __ATOMIC_ACQ_REL, __HIP_MEMORY_SCOPE_AGENT);
    while (__hip_atomic_load(cnt, __ATOMIC_ACQUIRE, __HIP_MEMORY_SCOPE_AGENT) < target)
      __builtin_amdgcn_s_sleep(8);
  }
  __syncthreads();
  __threadfence();
}

__global__ __launch_bounds__(256) void tree_kernel(const int* __restrict__ graphs,
    const int* __restrict__ edges, const float* __restrict__ edge_w,
    const float* __restrict__ edge_b, const float* __restrict__ semb_w,
    const float* __restrict__ semb_b, float* __restrict__ ws, float* __restrict__ out) {
  __shared__ float s_w[16384];      // W_e[:, q*64 .. q*64+63], k-interleaved by 4
  __shared__ float s_rp[8 * DIM];   // staged parent r-vectors
  __shared__ float s_out[8 * 64];   // reduced outputs per chunk
  __shared__ int s_par[256], s_depth[256], s_edge[256], s_list[256];
  __shared__ float s_red[256];
  __shared__ float s_dots[4];
  __shared__ int s_m, s_maxd;

  const int t = threadIdx.x;
  const int b = blockIdx.x;
  const int g = b & 15;    // graph; blocks of a graph share (b%8) -> same XCD
  const int i = b >> 4;    // 0..15
  const int e = i >> 2;    // edge type
  const int q = i & 3;     // quarter of output DIM
  const int lane = t & 63, wave = t >> 6;
  const int dq = lane & 15, ds2 = lane >> 4;
  const int kg = wave * 4 + ds2;   // 0..15, k-slice of 16

  float* rg = ws + OFF_R + (size_t)g * 256 * DIM;
  unsigned int* bar = (unsigned int*)(ws + OFF_BAR);
  float* Sg = ws + OFF_S;
  const float* base = ws + OFF_BASE;
  const float* cand = ws + OFF_CAND;

  // ---- setup: parents, depths, edges ----
  if (t == 0) { s_m = 0; s_maxd = 0; }
  s_par[t] = t + graphs[g * 256 + t];
  s_edge[t] = edges[t];
  __syncthreads();
  {
    int d = 0, k = t;
    while (k != 0) { k = s_par[k]; ++d; }
    s_depth[t] = d;
    atomicMax(&s_maxd, d);
  }
  // stage W slab: s_w[(k>>2)*256 + dl*4 + (k&3)] = W_e[q*64+dl][k]
  for (int idx = t; idx < 16384; idx += 256) {
    int k = idx & 255, dl = idx >> 8;
    s_w[((k >> 2) << 8) + dl * 4 + (k & 3)] =
        edge_w[e * DIM * DIM + (q * 64 + dl) * DIM + k];
  }
  // r_g[g][0] = score_emb_w
  if (e == 0 && t < 64) rg[q * 64 + t] = semb_w[q * 64 + t];
  __syncthreads();
  const int maxd = s_maxd;
  unsigned int bseq = 1;
  gbar(&bar[g], 16u * bseq); ++bseq;

  float preg = 0.f;

  // ---- level loop (top-down r propagation) ----
  for (int d = 1; d <= maxd; ++d) {
    if (t == 0) s_m = 0;
    __syncthreads();
    if (t > 0 && t < 255 && s_depth[t] == d && s_edge[t] == e) {
      int p = atomicAdd(&s_m, 1);
      s_list[p] = t;
    }
    __syncthreads();
    const int mt = s_m;
    for (int mb = 0; mb < mt; mb += 8) {
      const int mc = min(8, mt - mb);
      // stage parent r-vectors (zero-fill unused slots)
      for (int idx = t; idx < 8 * DIM; idx += 256) {
        int m = idx >> 8, k = idx & 255;
        float v = 0.f;
        if (m < mc) v = rg[(size_t)s_par[s_list[mb + m]] * DIM + k];
        s_rp[idx] = v;
      }
      for (int idx = t; idx < 8 * 64; idx += 256) s_out[idx] = 0.f;
      __syncthreads();

      float acc[8][4] = {};
      #pragma unroll
      for (int kbi = 0; kbi < 4; ++kbi) {
        const int kb = kg * 4 + kbi;
        float4 wv[4];
        #pragma unroll
        for (int dj = 0; dj < 4; ++dj)
          wv[dj] = *(const float4*)&s_w[(kb << 8) + (dq + 16 * dj) * 4];
        #pragma unroll
        for (int m = 0; m < 8; ++m) {
          const float4 rv = *(const float4*)&s_rp[m * DIM + kb * 4];
          #pragma unroll
          for (int dj = 0; dj < 4; ++dj) {
            acc[m][dj] = fmaf(rv.x, wv[dj].x, acc[m][dj]);
            acc[m][dj] = fmaf(rv.y, wv[dj].y, acc[m][dj]);
            acc[m][dj] = fmaf(rv.z, wv[dj].z, acc[m][dj]);
            acc[m][dj] = fmaf(rv.w, wv[dj].w, acc[m][dj]);
          }
        }
      }
      #pragma unroll
      for (int m = 0; m < 8; ++m) {
        #pragma unroll
        for (int dj = 0; dj < 4; ++dj)
          atomicAdd(&s_out[m * 64 + dq + 16 * dj], acc[m][dj]);
      }
      __syncthreads();
      // write r_c slices + accumulate score terms (this block's q-slice only)
      for (int idx = t; idx < mc * 64; idx += 256) {
        int m = idx >> 6, dl = idx & 63;
        int nd = s_list[mb + m];
        float rv = s_out[m * 64 + dl];
        rg[(size_t)nd * DIM + q * 64 + dl] = rv;
        preg = fmaf(rv, base[nd * DIM + q * 64 + dl], preg);
        preg = fmaf(s_rp[m * DIM + q * 64 + dl], edge_b[e * DIM + q * 64 + dl], preg);
      }
      __syncthreads();
    }
    gbar(&bar[g], 16u * bseq); ++bseq;
  }

  // ---- constants (one block per graph) + per-block score reduce ----
  if (i == 0) {
    preg = fmaf(semb_w[t], base[t] + semb_b[t], preg);  // w·(base_0 + seb)
    if (t == 0) preg += ws[OFF_DS];                     // data_score
  }
  s_red[t] = preg;
  __syncthreads();
  for (int off = 128; off > 0; off >>= 1) {
    if (t < off) s_red[t] += s_red[t + off];
    __syncthreads();
  }
  if (t == 0) atomicAdd(&Sg[g], s_red[0]);
  gbar(&bar[g], 16u * bseq); ++bseq;

  // ---- outputs (block i==0 of each graph) ----
  if (i == 0) {
    const int p255 = s_par[255];
    const float rv = rg[(size_t)p255 * DIM + t];
    for (int e2 = 0; e2 < 4; ++e2) {
      s_red[t] = rv * cand[e2 * DIM + t];
      __syncthreads();
      for (int off = 128; off > 0; off >>= 1) {
        if (t < off) s_red[t] += s_red[t + off];
        __syncthreads();
      }
      if (t == 0) s_dots[e2] = s_red[0];
      __syncthreads();
    }
    if (t == 0) {
      float S = __hip_atomic_load(&Sg[g], __ATOMIC_ACQUIRE, __HIP_MEMORY_SCOPE_AGENT);
      int cor = edges[255];
      int alts[3]; int na = 0;
      for (int ee = 0; ee < 4; ++ee) if (ee != cor) alts[na++] = ee;
      int first = (g == 0) ? cor : alts[2];
      out[g * 4 + 0] = S + s_dots[first];
      out[g * 4 + 1] = S + s_dots[alts[0]];
      out[g * 4 + 2] = S + s_dots[alts[1]];
      out[g * 4 + 3] = S + s_dots[alts[2]];
    }
  }
}

extern "C" void kernel_launch(void* const* d_in, const int* in_sizes, int n_in,
                              void* d_out, int out_size, void* d_ws, size_t ws_size,
                              hipStream_t stream) {
  (void)in_sizes; (void)n_in; (void)out_size; (void)ws_size;
  const int* data      = (const int*)d_in[0];
  const int* edges     = (const int*)d_in[2];
  const int* graphs    = (const int*)d_in[3];
  const float* data_vecs = (const float*)d_in[4];
  const float* data_w  = (const float*)d_in[5];
  const float* data_b  = (const float*)d_in[6];
  const float* edge_w  = (const float*)d_in[7];
  const float* edge_b  = (const float*)d_in[8];
  const float* semb_w  = (const float*)d_in[9];
  const float* semb_b  = (const float*)d_in[10];
  const float* sdw     = (const float*)d_in[11];
  const float* sdb     = (const float*)d_in[12];
  float* ws  = (float*)d_ws;
  float* out = (float*)d_out;

  // zero barrier counters + per-graph score accumulators
  hipMemsetAsync((char*)d_ws + (size_t)OFF_BAR * sizeof(float), 0, 192, stream);
  hipLaunchKernelGGL(base_kernel, dim3(256), dim3(256), 0, stream,
                     data, data_vecs, data_w, data_b, ws);
  hipLaunchKernelGGL(prep_kernel, dim3(5), dim3(256), 0, stream,
                     edge_w, edge_b, sdw, sdb, ws);

  void* args[] = { (void*)&graphs, (void*)&edges, (void*)&edge_w, (void*)&edge_b,
                   (void*)&semb_w, (void*)&semb_b, (void*)&ws, (void*)&out };
  hipError_t err = hipLaunchCooperativeKernel((void*)tree_kernel, dim3(256), dim3(256),
                                              args, 0, stream);
  if (err != hipSuccess) {
    // fallback: plain launch (256 blocks <= 256 CUs, 1 block/CU by LDS -> co-resident)
    hipLaunchKernelGGL(tree_kernel, dim3(256), dim3(256), 0, stream,
                       graphs, edges, edge_w, edge_b, semb_w, semb_b, ws, out);
  }
}

// Round 4
// 663.373 us; speedup vs baseline: 1.5190x; 1.5190x over previous
//
#include <hip/hip_runtime.h>

#define DIM 256
#define VDIM 300

// ws layout (float offsets)
#define OFF_BASE 0        // 256*256 floats (node embeddings)
#define OFF_R    65536    // 16*256*256 floats (per-graph r-vectors)

// ---------------- base: emb = data_vecs[data] @ data_w + data_b ----------------
__global__ __launch_bounds__(256) void base_kernel(const int* __restrict__ data,
    const float* __restrict__ data_vecs, const float* __restrict__ data_w,
    const float* __restrict__ data_b, float* __restrict__ ws) {
  __shared__ float s_v[VDIM];
  const int i = blockIdx.x, t = threadIdx.x;
  const int row = data[i];
  for (int k = t; k < VDIM; k += 256) s_v[k] = data_vecs[(size_t)row * VDIM + k];
  __syncthreads();
  float acc = data_b[t];
  for (int k = 0; k < VDIM; ++k) acc = fmaf(s_v[k], data_w[k * DIM + t], acc);
  ws[OFF_BASE + i * DIM + t] = acc;
}

// ---------------- per-tile matvec compute from W-registers ----------------
template <int MT>
__device__ __forceinline__ void tile_compute(const float4 (&w)[16],
    const float* __restrict__ s_rp, float* __restrict__ s_out4,
    const int kq, const int dd) {
  float acc[MT];
  #pragma unroll
  for (int m = 0; m < MT; ++m) acc[m] = 0.f;
  #pragma unroll
  for (int kk = 0; kk < 16; ++kk) {
    const float4 wv = w[kk];
    #pragma unroll
    for (int m = 0; m < MT; ++m) {
      const float4 rv = *(const float4*)(s_rp + m * DIM + kq * 64 + kk * 4);
      acc[m] = fmaf(wv.x, rv.x, acc[m]);
      acc[m] = fmaf(wv.y, rv.y, acc[m]);
      acc[m] = fmaf(wv.z, rv.z, acc[m]);
      acc[m] = fmaf(wv.w, rv.w, acc[m]);
    }
  }
  #pragma unroll
  for (int m = 0; m < MT; ++m) s_out4[(kq * 8 + m) * DIM + dd] = acc[m];
}

// ---------------- tree: ONE block (1024 thr) per graph, zero cross-block sync ----
__global__ __launch_bounds__(1024) void tree_kernel(
    const int* __restrict__ graphs, const int* __restrict__ edges,
    const float* __restrict__ edge_w, const float* __restrict__ edge_b,
    const float* __restrict__ semb_w, const float* __restrict__ semb_b,
    const float* __restrict__ sdw, const float* __restrict__ sdb,
    float* __restrict__ ws, float* __restrict__ out) {
  __shared__ float s_rp[8 * DIM];       // staged parent r-vectors (8 KB)
  __shared__ float s_out4[4 * 8 * DIM]; // k-quarter partials [kq][m][dd] (32 KB)
  __shared__ float s_be[4 * DIM];       // edge biases (4 KB)
  __shared__ float s_cand[4 * DIM];     // candidate vectors for node 255 (4 KB)
  __shared__ float s_red[1024];         // reduction scratch (4 KB)
  __shared__ int s_par[256], s_depth[256], s_edge[256];
  __shared__ int s_list[4 * 256];
  __shared__ int s_cnt[4];
  __shared__ int s_maxd;
  __shared__ float s_ds;

  const int t = threadIdx.x;
  const int g = blockIdx.x;
  const int dd = t & 255;   // output dim
  const int kq = t >> 8;    // k-quarter 0..3

  const float* base = ws + OFF_BASE;
  float* rg = ws + OFF_R + (size_t)g * 256 * DIM;

  // ---- setup ----
  if (t == 0) s_maxd = 0;
  if (t < 256) {
    s_par[t] = t + graphs[g * 256 + t];
    s_edge[t] = edges[t];
  }
  s_be[t] = edge_b[t];  // 4*256 == 1024
  __syncthreads();
  if (t < 256) {
    int dpt = 0, k = t;
    while (k != 0) { k = s_par[k]; ++dpt; }
    s_depth[t] = dpt;
    atomicMax(&s_maxd, dpt);
    rg[t] = semb_w[t];                 // r(root) = score_emb_w
    s_rp[t] = base[255 * DIM + t];     // stage base_255 for cand/data_score
  }
  __syncthreads();
  // cand_e[dd] = sum_d b255[d] * W[e][d][dd] + be[e][dd]   (e = kq)
  {
    const int e = kq;
    float acc = s_be[e * DIM + dd];
    const float* Wp = edge_w + (size_t)e * DIM * DIM + dd;
    for (int d0 = 0; d0 < DIM; ++d0)
      acc = fmaf(s_rp[d0], Wp[(size_t)d0 * DIM], acc);
    s_cand[e * DIM + dd] = acc;
  }
  // data_score = dot(b255 + sdb, sdw)
  s_red[t] = (t < 256) ? (s_rp[t] + sdb[t]) * sdw[t] : 0.f;
  __syncthreads();
  for (int off = 512; off > 0; off >>= 1) {
    if (t < off) s_red[t] += s_red[t + off];
    __syncthreads();
  }
  if (t == 0) s_ds = s_red[0];
  __syncthreads();

  const int maxd = s_maxd;
  float preg = 0.f;

  // ---- level loop (parents of level d are exactly at level d-1) ----
  for (int d = 1; d <= maxd; ++d) {
    if (t < 4) s_cnt[t] = 0;
    __syncthreads();
    if (t > 0 && t < 255 && s_depth[t] == d) {
      const int e = s_edge[t];
      const int p = atomicAdd(&s_cnt[e], 1);
      s_list[e * 256 + p] = t;
    }
    __syncthreads();

    for (int e = 0; e < 4; ++e) {
      const int B = s_cnt[e];
      if (B == 0) continue;
      // W row-chunk -> registers, ONCE per (level,edge) pass
      float4 w[16];
      {
        const float* Wp = edge_w + ((size_t)e * DIM + dd) * DIM + kq * 64;
        #pragma unroll
        for (int kk = 0; kk < 16; ++kk) w[kk] = *(const float4*)(Wp + kk * 4);
      }
      int mb = 0;
      while (mb < B) {
        const int rem = B - mb;
        const int mt = rem >= 5 ? 8 : (rem >= 3 ? 4 : rem);  // padded tile size
        const int mv = (rem < mt) ? rem : mt;                // valid rows
        // stage parent r-vectors (zero-pad)
        for (int idx = t; idx < mt * 64; idx += 1024) {
          const int m = idx >> 6, k4 = idx & 63;
          float4 v = make_float4(0.f, 0.f, 0.f, 0.f);
          if (m < mv) {
            const int nd = s_list[e * 256 + mb + m];
            v = *(const float4*)(rg + (size_t)s_par[nd] * DIM + k4 * 4);
          }
          *(float4*)(s_rp + m * DIM + k4 * 4) = v;
        }
        __syncthreads();
        if (mt == 8)      tile_compute<8>(w, s_rp, s_out4, kq, dd);
        else if (mt == 4) tile_compute<4>(w, s_rp, s_out4, kq, dd);
        else if (mt == 2) tile_compute<2>(w, s_rp, s_out4, kq, dd);
        else              tile_compute<1>(w, s_rp, s_out4, kq, dd);
        __syncthreads();
        // reduce k-quarters, write r_c, accumulate score terms
        for (int idx = t; idx < mv * 64; idx += 1024) {
          const int m = idx >> 6, k4 = idx & 63;
          const int nd = s_list[e * 256 + mb + m];
          float4 a0 = *(const float4*)(s_out4 + (0 * 8 + m) * DIM + k4 * 4);
          float4 a1 = *(const float4*)(s_out4 + (1 * 8 + m) * DIM + k4 * 4);
          float4 a2 = *(const float4*)(s_out4 + (2 * 8 + m) * DIM + k4 * 4);
          float4 a3 = *(const float4*)(s_out4 + (3 * 8 + m) * DIM + k4 * 4);
          float4 rv; rv.x = (a0.x + a1.x) + (a2.x + a3.x);
          rv.y = (a0.y + a1.y) + (a2.y + a3.y);
          rv.z = (a0.z + a1.z) + (a2.z + a3.z);
          rv.w = (a0.w + a1.w) + (a2.w + a3.w);
          *(float4*)(rg + (size_t)nd * DIM + k4 * 4) = rv;
          const float4 bs = *(const float4*)(base + (size_t)nd * DIM + k4 * 4);
          const float4 rp = *(const float4*)(s_rp + m * DIM + k4 * 4);
          const float4 be = *(const float4*)(s_be + e * DIM + k4 * 4);
          preg += rv.x * bs.x + rv.y * bs.y + rv.z * bs.z + rv.w * bs.w;
          preg += rp.x * be.x + rp.y * be.y + rp.z * be.z + rp.w * be.w;
        }
        __syncthreads();
        mb += mt;
      }
    }
  }

  // ---- score_common: root term + block-wide reduce ----
  if (t < 256) preg = fmaf(semb_w[t], base[t] + semb_b[t], preg);
  s_red[t] = preg;
  __syncthreads();
  for (int off = 512; off > 0; off >>= 1) {
    if (t < off) s_red[t] += s_red[t + off];
    __syncthreads();
  }
  const float S = s_red[0] + s_ds;
  __syncthreads();

  // ---- 4 candidate dots: segment e2 = kq reduces rv*cand ----
  const int p255 = s_par[255];
  s_red[t] = rg[(size_t)p255 * DIM + dd] * s_cand[kq * DIM + dd];
  __syncthreads();
  for (int off = 128; off > 0; off >>= 1) {
    if ((t & 255) < off) s_red[t] += s_red[t + off];
    __syncthreads();
  }
  if (t == 0) {
    const int cor = s_edge[255];
    int alts[3]; int na = 0;
    for (int ee = 0; ee < 4; ++ee) if (ee != cor) alts[na++] = ee;
    const int first = (g == 0) ? cor : alts[2];
    const float dots[4] = { s_red[0], s_red[256], s_red[512], s_red[768] };
    out[g * 4 + 0] = S + dots[first];
    out[g * 4 + 1] = S + dots[alts[0]];
    out[g * 4 + 2] = S + dots[alts[1]];
    out[g * 4 + 3] = S + dots[alts[2]];
  }
}

extern "C" void kernel_launch(void* const* d_in, const int* in_sizes, int n_in,
                              void* d_out, int out_size, void* d_ws, size_t ws_size,
                              hipStream_t stream) {
  (void)in_sizes; (void)n_in; (void)out_size; (void)ws_size;
  const int* data        = (const int*)d_in[0];
  const int* edges       = (const int*)d_in[2];
  const int* graphs      = (const int*)d_in[3];
  const float* data_vecs = (const float*)d_in[4];
  const float* data_w    = (const float*)d_in[5];
  const float* data_b    = (const float*)d_in[6];
  const float* edge_w    = (const float*)d_in[7];
  const float* edge_b    = (const float*)d_in[8];
  const float* semb_w    = (const float*)d_in[9];
  const float* semb_b    = (const float*)d_in[10];
  const float* sdw       = (const float*)d_in[11];
  const float* sdb       = (const float*)d_in[12];
  float* ws  = (float*)d_ws;
  float* out = (float*)d_out;

  hipLaunchKernelGGL(base_kernel, dim3(256), dim3(256), 0, stream,
                     data, data_vecs, data_w, data_b, ws);
  hipLaunchKernelGGL(tree_kernel, dim3(16), dim3(1024), 0, stream,
                     graphs, edges, edge_w, edge_b, semb_w, semb_b, sdw, sdb,
                     ws, out);
}